// Round 1
// baseline (476.779 us; speedup 1.0000x reference)
//
#include <hip/hip_runtime.h>

#define BB 4
#define SS 2048
#define HH 8
#define MM 16
#define SCALE 0.25f

#define QT 128
#define KT 128
#define KPAD 20

static constexpr size_t NQKV = (size_t)BB * HH * SS * MM;  // 1,048,576 floats (4 MB)

// ---------------- Kernel 1: Q/K/V projections ----------------
// one thread per (b, s, h); x row -> 3x dense 16x16 matvec + bias
__device__ __forceinline__ void proj16(const float xr[16], const float* __restrict__ w,
                                       const float* __restrict__ bias, int h, float out[16]) {
#pragma unroll
    for (int i = 0; i < 16; i++) out[i] = bias[(h << 4) + i];
#pragma unroll
    for (int j = 0; j < 16; j++) {
        float xj = xr[j];
        const float* wr = w + (((j * HH) + h) << 4);
#pragma unroll
        for (int i = 0; i < 16; i++) out[i] = fmaf(xj, wr[i], out[i]);
    }
}

__global__ __launch_bounds__(256) void proj_kernel(
    const float* __restrict__ x,
    const float* __restrict__ wq, const float* __restrict__ bq,
    const float* __restrict__ wk, const float* __restrict__ bk,
    const float* __restrict__ wv, const float* __restrict__ bv,
    float* __restrict__ qb, float* __restrict__ kb, float* __restrict__ vb)
{
    int idx = blockIdx.x * 256 + threadIdx.x;   // over B*S*H = 65536
    int h  = idx & 7;
    int bs = idx >> 3;                          // b*S + s
    int b  = bs >> 11;
    int s  = bs & 2047;

    float xr[16];
    const float4* x4 = (const float4*)(x + (size_t)bs * MM);
#pragma unroll
    for (int j = 0; j < 4; j++) {
        float4 t = x4[j];
        xr[j * 4 + 0] = t.x; xr[j * 4 + 1] = t.y; xr[j * 4 + 2] = t.z; xr[j * 4 + 3] = t.w;
    }

    size_t orow = (((size_t)(b * HH + h) * SS) + s) * MM;
    float o[16];

    proj16(xr, wq, bq, h, o);
#pragma unroll
    for (int j = 0; j < 4; j++) ((float4*)(qb + orow))[j] = make_float4(o[j*4], o[j*4+1], o[j*4+2], o[j*4+3]);

    proj16(xr, wk, bk, h, o);
#pragma unroll
    for (int j = 0; j < 4; j++) ((float4*)(kb + orow))[j] = make_float4(o[j*4], o[j*4+1], o[j*4+2], o[j*4+3]);

    proj16(xr, wv, bv, h, o);
#pragma unroll
    for (int j = 0; j < 4; j++) ((float4*)(vb + orow))[j] = make_float4(o[j*4], o[j*4+1], o[j*4+2], o[j*4+3]);
}

// ---------------- Kernel 2: flash attention (fp32 vector) ----------------
// one thread per query row; online softmax over all keys; K/V tiles in LDS
__global__ __launch_bounds__(128) void attn_kernel(
    const float* __restrict__ qb, const float* __restrict__ kb,
    const float* __restrict__ vb, float* __restrict__ hb)
{
    __shared__ float Kt[KT][KPAD];
    __shared__ float Vt[KT][KPAD];

    int t = threadIdx.x;
    int b = blockIdx.z, h = blockIdx.y;
    int q = blockIdx.x * QT + t;
    size_t headbase = (size_t)(b * HH + h) * SS * MM;

    float qr[16];
    const float4* q4 = (const float4*)(qb + headbase + (size_t)q * MM);
#pragma unroll
    for (int j = 0; j < 4; j++) {
        float4 tq = q4[j];
        qr[j * 4 + 0] = tq.x; qr[j * 4 + 1] = tq.y; qr[j * 4 + 2] = tq.z; qr[j * 4 + 3] = tq.w;
    }

    float m = -1e30f, l = 0.0f;
    float acc[16];
#pragma unroll
    for (int i = 0; i < 16; i++) acc[i] = 0.0f;

    for (int k0 = 0; k0 < SS; k0 += KT) {
        // stage K/V tile
        const float4* k4 = (const float4*)(kb + headbase + (size_t)(k0 + t) * MM);
        const float4* v4 = (const float4*)(vb + headbase + (size_t)(k0 + t) * MM);
#pragma unroll
        for (int j = 0; j < 4; j++) {
            float4 kv = k4[j];
            Kt[t][j*4+0] = kv.x; Kt[t][j*4+1] = kv.y; Kt[t][j*4+2] = kv.z; Kt[t][j*4+3] = kv.w;
            float4 vv = v4[j];
            Vt[t][j*4+0] = vv.x; Vt[t][j*4+1] = vv.y; Vt[t][j*4+2] = vv.z; Vt[t][j*4+3] = vv.w;
        }
        __syncthreads();

        for (int kk = 0; kk < KT; kk++) {
            float s0 = 0.f, s1 = 0.f, s2 = 0.f, s3 = 0.f;
#pragma unroll
            for (int i = 0; i < 4; i++) {
                s0 = fmaf(qr[i +  0], Kt[kk][i +  0], s0);
                s1 = fmaf(qr[i +  4], Kt[kk][i +  4], s1);
                s2 = fmaf(qr[i +  8], Kt[kk][i +  8], s2);
                s3 = fmaf(qr[i + 12], Kt[kk][i + 12], s3);
            }
            float sc = ((s0 + s1) + (s2 + s3)) * SCALE;
            float p;
            if (sc > m) {
                float c = __expf(m - sc);
                l *= c;
#pragma unroll
                for (int i = 0; i < 16; i++) acc[i] *= c;
                m = sc;
                p = 1.0f;
            } else {
                p = __expf(sc - m);
            }
            l += p;
#pragma unroll
            for (int i = 0; i < 16; i++) acc[i] = fmaf(p, Vt[kk][i], acc[i]);
        }
        __syncthreads();
    }

    float inv = 1.0f / l;
    float* outp = hb + headbase + (size_t)q * MM;
#pragma unroll
    for (int j = 0; j < 4; j++) {
        ((float4*)outp)[j] = make_float4(acc[j*4]*inv, acc[j*4+1]*inv, acc[j*4+2]*inv, acc[j*4+3]*inv);
    }
}

// ---------------- Kernel 3: output projection ----------------
// one thread per (b, s): out[b,s,i] = sum_{h,j} head[b,h,s,j] * wo[h,j,i] + bo[i]
__global__ __launch_bounds__(256) void outproj_kernel(
    const float* __restrict__ hb, const float* __restrict__ wo,
    const float* __restrict__ bo, float* __restrict__ out)
{
    int idx = blockIdx.x * 256 + threadIdx.x;   // over B*S = 8192
    int b = idx >> 11;
    int s = idx & 2047;

    float acc[16];
#pragma unroll
    for (int i = 0; i < 16; i++) acc[i] = bo[i];

    for (int h = 0; h < HH; h++) {
        const float* hr = hb + ((size_t)(b * HH + h) * SS + s) * MM;
        float hv[16];
        const float4* h4 = (const float4*)hr;
#pragma unroll
        for (int j = 0; j < 4; j++) {
            float4 tv = h4[j];
            hv[j*4+0] = tv.x; hv[j*4+1] = tv.y; hv[j*4+2] = tv.z; hv[j*4+3] = tv.w;
        }
#pragma unroll
        for (int j = 0; j < 16; j++) {
            float hj = hv[j];
            const float* wr = wo + (((h << 4) + j) << 4);
#pragma unroll
            for (int i = 0; i < 16; i++) acc[i] = fmaf(hj, wr[i], acc[i]);
        }
    }

    float* op = out + (size_t)idx * MM;
#pragma unroll
    for (int j = 0; j < 4; j++) {
        ((float4*)op)[j] = make_float4(acc[j*4], acc[j*4+1], acc[j*4+2], acc[j*4+3]);
    }
}

extern "C" void kernel_launch(void* const* d_in, const int* in_sizes, int n_in,
                              void* d_out, int out_size, void* d_ws, size_t ws_size,
                              hipStream_t stream) {
    const float* x  = (const float*)d_in[0];
    const float* wq = (const float*)d_in[1];
    const float* bq = (const float*)d_in[2];
    const float* wk = (const float*)d_in[3];
    const float* bk = (const float*)d_in[4];
    const float* wv = (const float*)d_in[5];
    const float* bv = (const float*)d_in[6];
    const float* wo = (const float*)d_in[7];
    const float* bo = (const float*)d_in[8];
    float* out = (float*)d_out;

    float* ws = (float*)d_ws;
    float* qb = ws;
    float* kb = ws + NQKV;
    float* vb = ws + 2 * NQKV;
    float* hb = ws + 3 * NQKV;

    proj_kernel<<<256, 256, 0, stream>>>(x, wq, bq, wk, bk, wv, bv, qb, kb, vb);
    attn_kernel<<<dim3(SS / QT, HH, BB), 128, 0, stream>>>(qb, kb, vb, hb);
    outproj_kernel<<<(BB * SS) / 256, 256, 0, stream>>>(hb, wo, bo, out);
}

// Round 2
// 72.142 us; speedup vs baseline: 6.6089x; 6.6089x over previous
//
#include <hip/hip_runtime.h>

#define BB 4
#define SS 2048
#define HH 8
#define MM 16

// 0.25 (= 1/sqrt(16)) * log2(e): fold softmax scale + exp->exp2 conversion into Q
#define QSCALE 0.36067376022224085f

typedef __attribute__((ext_vector_type(8)))  short short8;
typedef __attribute__((ext_vector_type(4)))  int   int4v;
typedef __attribute__((ext_vector_type(4)))  float f32x4;
typedef __attribute__((ext_vector_type(16))) float f32x16;

static constexpr size_t NQKV = (size_t)BB * HH * SS * MM;  // 1,048,576 elements

__device__ __forceinline__ int pk_bf16(float lo, float hi) {
    int r;
    asm("v_cvt_pk_bf16_f32 %0, %1, %2" : "=v"(r) : "v"(lo), "v"(hi));
    return r;
}

// ---------------- Kernel 1: Q/K/V projections (writes bf16) ----------------
__device__ __forceinline__ void proj16(const float xr[16], const float* __restrict__ w,
                                       const float* __restrict__ bias, int h, float out[16]) {
#pragma unroll
    for (int i = 0; i < 16; i++) out[i] = bias[(h << 4) + i];
#pragma unroll
    for (int j = 0; j < 16; j++) {
        float xj = xr[j];
        const float* wr = w + (((j * HH) + h) << 4);
#pragma unroll
        for (int i = 0; i < 16; i++) out[i] = fmaf(xj, wr[i], out[i]);
    }
}

__device__ __forceinline__ void pack_store(ushort* dst, const float o[16], float scale) {
    int4v w0, w1;
#pragma unroll
    for (int j = 0; j < 4; j++) w0[j] = pk_bf16(o[2*j] * scale,     o[2*j+1] * scale);
#pragma unroll
    for (int j = 0; j < 4; j++) w1[j] = pk_bf16(o[8+2*j] * scale,   o[8+2*j+1] * scale);
    int4v* p = (int4v*)dst;
    p[0] = w0; p[1] = w1;
}

__global__ __launch_bounds__(256) void proj_kernel(
    const float* __restrict__ x,
    const float* __restrict__ wq, const float* __restrict__ bq,
    const float* __restrict__ wk, const float* __restrict__ bk,
    const float* __restrict__ wv, const float* __restrict__ bv,
    ushort* __restrict__ qb, ushort* __restrict__ kb, ushort* __restrict__ vb)
{
    int idx = blockIdx.x * 256 + threadIdx.x;   // over B*S*H = 65536
    int h  = idx & 7;
    int bs = idx >> 3;
    int b  = bs >> 11;
    int s  = bs & 2047;

    float xr[16];
    const float4* x4 = (const float4*)(x + (size_t)bs * MM);
#pragma unroll
    for (int j = 0; j < 4; j++) {
        float4 t = x4[j];
        xr[j*4+0] = t.x; xr[j*4+1] = t.y; xr[j*4+2] = t.z; xr[j*4+3] = t.w;
    }

    size_t orow = (((size_t)(b * HH + h) * SS) + s) * MM;
    float o[16];

    proj16(xr, wq, bq, h, o);  pack_store(qb + orow, o, QSCALE);
    proj16(xr, wk, bk, h, o);  pack_store(kb + orow, o, 1.0f);
    proj16(xr, wv, bv, h, o);  pack_store(vb + orow, o, 1.0f);
}

// ---------------- Kernel 2: MFMA flash attention ----------------
// 4 waves/block, 32 queries/wave (128 q/block). K-tile 128 keys staged to LDS.
// QK^T swapped: S^T = mfma(K, Q) -> lane owns 16 key-scores for query (lane&31).
// PV: O^T = mfma(V^T, P^T) twice per 32-key subtile.
__global__ __launch_bounds__(256) void attn_kernel(
    const ushort* __restrict__ qb, const ushort* __restrict__ kb,
    const ushort* __restrict__ vb, float* __restrict__ hb)
{
    __shared__ ushort Klds[128 * 24];   // row stride 24 shorts (48 B) - conflict-spread
    __shared__ ushort Vt[16 * 136];     // V^T, row stride 136 shorts (272 B)

    int tid = threadIdx.x;
    // XCD-aware swizzle: 512 blocks -> each XCD owns 4 consecutive (b,h) pairs
    int nb = ((blockIdx.x & 7) << 6) | (blockIdx.x >> 3);
    int bh = nb >> 4, qt = nb & 15;
    size_t base = (size_t)bh * SS * MM;
    const ushort* Qg = qb + base;
    const ushort* Kg = kb + base;
    const ushort* Vg = vb + base;

    int lane = tid & 63, wid = tid >> 6;
    int n = lane & 31, c = lane >> 5;
    int q = qt * 128 + wid * 32 + n;

    // Q fragment (B-operand): lane holds Q[q][8c..8c+7], pre-scaled bf16
    short8 qf = *(const short8*)(Qg + (size_t)q * MM + c * 8);

    f32x16 oacc = 0;
    const f32x16 zacc = 0;
    float m = -1e30f, l = 0.0f;

    int srow = tid >> 1, shalf = tid & 1;

    for (int kt = 0; kt < SS / 128; kt++) {
        // issue global loads early
        int4v kw = *(const int4v*)(Kg + (size_t)((kt << 7) + srow) * MM + shalf * 8);
        int4v vw = *(const int4v*)(Vg + (size_t)((kt << 7) + srow) * MM + shalf * 8);
        __syncthreads();
        *(int4v*)&Klds[srow * 24 + shalf * 8] = kw;
        union { int4v v; ushort s[8]; } vu; vu.v = vw;
#pragma unroll
        for (int j = 0; j < 8; j++) Vt[(8 * shalf + j) * 136 + srow] = vu.s[j];
        __syncthreads();

#pragma unroll
        for (int sub = 0; sub < 4; sub++) {
            // A-operand: K rows = subtile keys; lane holds K[key=n][8c..8c+7]
            short8 kf = *(const short8*)&Klds[(sub * 32 + n) * 24 + c * 8];
            f32x16 s = __builtin_amdgcn_mfma_f32_32x32x16_bf16(kf, qf, zacc, 0, 0, 0);
            // lane holds 16 scores (keys (r&3)+8*(r>>2)+4c) for query q, log2-units

            // ---- row max (16 regs, then cross-half combine) ----
            float t8[8];
#pragma unroll
            for (int i = 0; i < 8; i++) t8[i] = fmaxf(s[2*i], s[2*i+1]);
            float t4a = fmaxf(t8[0], t8[1]), t4b = fmaxf(t8[2], t8[3]);
            float t4c = fmaxf(t8[4], t8[5]), t4d = fmaxf(t8[6], t8[7]);
            float pm = fmaxf(fmaxf(t4a, t4b), fmaxf(t4c, t4d));
            float xa = pm, xb = pm;
            asm("v_permlane32_swap_b32 %0, %1" : "+v"(xa), "+v"(xb));
            pm = fmaxf(xa, xb);

            float nm = fmaxf(m, pm);
            float corr = __builtin_amdgcn_exp2f(m - nm);
            m = nm;
            l *= corr;
#pragma unroll
            for (int r = 0; r < 8; r++) oacc[r] *= corr;

            // ---- exp2 ----
            float p[16];
#pragma unroll
            for (int r = 0; r < 16; r++) p[r] = __builtin_amdgcn_exp2f(s[r] - nm);

            // ---- sum (16 regs + cross-half) ----
            float u8[8];
#pragma unroll
            for (int i = 0; i < 8; i++) u8[i] = p[2*i] + p[2*i+1];
            float u4a = u8[0] + u8[1], u4b = u8[2] + u8[3];
            float u4c = u8[4] + u8[5], u4d = u8[6] + u8[7];
            float sm = (u4a + u4b) + (u4c + u4d);
            float ya = sm, yb = sm;
            asm("v_permlane32_swap_b32 %0, %1" : "+v"(ya), "+v"(yb));
            l += ya + yb;

            // ---- pack P to bf16, build PV B-operand frags via permlane swaps ----
            int a0 = pk_bf16(p[0],  p[1]);
            int a1 = pk_bf16(p[2],  p[3]);
            int a2 = pk_bf16(p[4],  p[5]);
            int a3 = pk_bf16(p[6],  p[7]);
            int a4 = pk_bf16(p[8],  p[9]);
            int a5 = pk_bf16(p[10], p[11]);
            int a6 = pk_bf16(p[12], p[13]);
            int a7 = pk_bf16(p[14], p[15]);

            int w0 = a0, w2 = a2;
            asm("v_permlane32_swap_b32 %0, %1" : "+v"(w0), "+v"(w2));
            int w1 = a1, w3 = a3;
            asm("v_permlane32_swap_b32 %0, %1" : "+v"(w1), "+v"(w3));
            int u0 = a4, u2 = a6;
            asm("v_permlane32_swap_b32 %0, %1" : "+v"(u0), "+v"(u2));
            int u1 = a5, u3 = a7;
            asm("v_permlane32_swap_b32 %0, %1" : "+v"(u1), "+v"(u3));

            int4v bi1 = {w0, w1, w2, w3};
            int4v bi2 = {u0, u1, u2, u3};
            short8 B1 = __builtin_bit_cast(short8, bi1);
            short8 B2 = __builtin_bit_cast(short8, bi2);

            // A-operand: V^T rows (d = lane&15, lanes 16-31 broadcast-duplicate)
            int d = lane & 15;
            short8 vf1 = *(const short8*)&Vt[d * 136 + sub * 32 + c * 8];
            short8 vf2 = *(const short8*)&Vt[d * 136 + sub * 32 + 16 + c * 8];
            oacc = __builtin_amdgcn_mfma_f32_32x32x16_bf16(vf1, B1, oacc, 0, 0, 0);
            oacc = __builtin_amdgcn_mfma_f32_32x32x16_bf16(vf2, B2, oacc, 0, 0, 0);
        }
    }

    // epilogue: O^T regs 0-7 hold d = {0-3,8-11} + 4c for query q
    float inv = 1.0f / l;
    float* orow = hb + base + (size_t)q * MM;
    f32x4 o0 = {oacc[0] * inv, oacc[1] * inv, oacc[2] * inv, oacc[3] * inv};
    f32x4 o1 = {oacc[4] * inv, oacc[5] * inv, oacc[6] * inv, oacc[7] * inv};
    *(f32x4*)(orow + 4 * c) = o0;
    *(f32x4*)(orow + 8 + 4 * c) = o1;
}

// ---------------- Kernel 3: output projection ----------------
__global__ __launch_bounds__(256) void outproj_kernel(
    const float* __restrict__ hb, const float* __restrict__ wo,
    const float* __restrict__ bo, float* __restrict__ out)
{
    int idx = blockIdx.x * 256 + threadIdx.x;   // over B*S = 8192
    int b = idx >> 11;

    float acc[16];
#pragma unroll
    for (int i = 0; i < 16; i++) acc[i] = bo[i];

    for (int h = 0; h < HH; h++) {
        const float* hr = hb + ((size_t)(b * HH + h) * SS + (idx & 2047)) * MM;
        float hv[16];
        const float4* h4 = (const float4*)hr;
#pragma unroll
        for (int j = 0; j < 4; j++) {
            float4 tv = h4[j];
            hv[j*4+0] = tv.x; hv[j*4+1] = tv.y; hv[j*4+2] = tv.z; hv[j*4+3] = tv.w;
        }
#pragma unroll
        for (int j = 0; j < 16; j++) {
            float hj = hv[j];
            const float* wr = wo + (((h << 4) + j) << 4);
#pragma unroll
            for (int i = 0; i < 16; i++) acc[i] = fmaf(hj, wr[i], acc[i]);
        }
    }

    float* op = out + (size_t)idx * MM;
#pragma unroll
    for (int j = 0; j < 4; j++) {
        ((float4*)op)[j] = make_float4(acc[j*4], acc[j*4+1], acc[j*4+2], acc[j*4+3]);
    }
}

extern "C" void kernel_launch(void* const* d_in, const int* in_sizes, int n_in,
                              void* d_out, int out_size, void* d_ws, size_t ws_size,
                              hipStream_t stream) {
    const float* x  = (const float*)d_in[0];
    const float* wq = (const float*)d_in[1];
    const float* bq = (const float*)d_in[2];
    const float* wk = (const float*)d_in[3];
    const float* bk = (const float*)d_in[4];
    const float* wv = (const float*)d_in[5];
    const float* bv = (const float*)d_in[6];
    const float* wo = (const float*)d_in[7];
    const float* bo = (const float*)d_in[8];
    float* out = (float*)d_out;

    ushort* qb = (ushort*)d_ws;
    ushort* kb = qb + NQKV;
    ushort* vb = kb + NQKV;
    float*  hbf = (float*)(vb + NQKV);   // 6 MB offset, 4 MB of fp32 head outputs

    proj_kernel<<<256, 256, 0, stream>>>(x, wq, bq, wk, bk, wv, bv, qb, kb, vb);
    attn_kernel<<<512, 256, 0, stream>>>(qb, kb, vb, hbf);
    outproj_kernel<<<32, 256, 0, stream>>>(hbf, wo, bo, out);
}